// Round 15
// baseline (465.828 us; speedup 1.0000x reference)
//
#include <hip/hip_runtime.h>
#include <hip/hip_bf16.h>
#include <stdint.h>

// Problem constants
#define B_   4
#define T_   1024
#define D_   1024
#define E_   8
#define FF_  2048
#define NT_  4096            // B*T tokens
#define LCAP 9472            // padded pairs + 256-tile overread headroom
#define NTS1 (D_ / 64)       // 16 K-steps, stage1 (BK=64)
#define NTS2 (FF_ / 64)      // 32 K-steps, stage2 (BK=64)

typedef unsigned short u16;
typedef __attribute__((ext_vector_type(8))) short bf16x8;   // 8 bf16 = 4 VGPRs
typedef __attribute__((ext_vector_type(4))) float f32x4;

#define MFMA16(a, b, c) __builtin_amdgcn_mfma_f32_16x16x32_bf16((a), (b), (c), 0, 0, 0)

__device__ __forceinline__ u16 f2bf(float f) {
  union { float f; uint32_t u; } c; c.f = f;
  return (u16)((c.u + 0x7FFFu + ((c.u >> 16) & 1u)) >> 16);   // RNE
}

__device__ __forceinline__ void gl_lds16(const void* g, void* l) {
  __builtin_amdgcn_global_load_lds(
      (const __attribute__((address_space(1))) uint32_t*)g,
      (__attribute__((address_space(3))) uint32_t*)l, 16, 0, 0);
}

// ---------------- small kernels ----------------

// one wave per token: router scores + out=x copy + xb=bf16(x); absorbs init.
__global__ __launch_bounds__(256) void k_router(const float* __restrict__ x,
                                                const float* __restrict__ rw,
                                                const float* __restrict__ rb,
                                                const float* __restrict__ temp,
                                                float* __restrict__ scores,
                                                float* __restrict__ out,
                                                u16* __restrict__ xb,
                                                int* __restrict__ tok, float* __restrict__ gate,
                                                int* __restrict__ cnt, int* __restrict__ cur) {
  const int gid = blockIdx.x * 256 + threadIdx.x;
  if (gid < LCAP) { tok[gid] = 0; gate[gid] = 0.f; }
  if (gid < E_)   { cnt[gid] = 0; cur[gid] = 0; }

  int wid  = gid >> 6;   // token id
  int lane = threadIdx.x & 63;
  const float* xr = x + (size_t)wid * D_;
  float* orow = out + (size_t)wid * D_;
  u16* xrow = xb + (size_t)wid * D_;
  float acc[E_];
  #pragma unroll
  for (int e = 0; e < E_; ++e) acc[e] = 0.f;
  for (int i = lane; i < D_; i += 64) {
    float xv = xr[i];
    orow[i] = xv;
    xrow[i] = f2bf(xv);
    #pragma unroll
    for (int e = 0; e < E_; ++e) acc[e] += xv * rw[e * D_ + i];
  }
  float inv = 1.0f / fmaxf(temp[0], 0.1f);
  #pragma unroll
  for (int e = 0; e < E_; ++e) {
    float v = acc[e];
    for (int off = 32; off; off >>= 1) v += __shfl_xor(v, off);
    if (lane == 0) scores[(size_t)wid * E_ + e] = (v + rb[e]) * inv;
  }
}

// one block per batch b; thread t owns token row [b,t]; 3 Sinkhorn iters + top-2.
__global__ __launch_bounds__(1024) void k_sinkhorn(const float* __restrict__ scores,
                                                   float* __restrict__ tkg, int* __restrict__ tki,
                                                   int* __restrict__ cnt) {
  const int b = blockIdx.x, t = threadIdx.x;
  const int row = b * T_ + t;
  float s[E_];
  #pragma unroll
  for (int e = 0; e < E_; ++e) s[e] = scores[(size_t)row * E_ + e];

  __shared__ float red[16][E_];
  __shared__ float redv[E_];
  __shared__ int lcnt[E_];
  if (t < E_) lcnt[t] = 0;
  const int wid = t >> 6, lane = t & 63;

  for (int it = 0; it < 3; ++it) {
    float m = s[0];
    #pragma unroll
    for (int e = 1; e < E_; ++e) m = fmaxf(m, s[e]);
    float sum = 0.f;
    #pragma unroll
    for (int e = 0; e < E_; ++e) sum += expf(s[e] - m);
    float lse = m + logf(sum);
    #pragma unroll
    for (int e = 0; e < E_; ++e) s[e] -= lse;

    #pragma unroll
    for (int e = 0; e < E_; ++e) {
      float v = s[e];
      for (int off = 32; off; off >>= 1) v = fmaxf(v, __shfl_xor(v, off));
      if (lane == 0) red[wid][e] = v;
    }
    __syncthreads();
    if (t < E_) {
      float mm = red[0][t];
      #pragma unroll
      for (int wv = 1; wv < 16; ++wv) mm = fmaxf(mm, red[wv][t]);
      redv[t] = mm;
    }
    __syncthreads();
    float cm[E_];
    #pragma unroll
    for (int e = 0; e < E_; ++e) cm[e] = redv[e];

    #pragma unroll
    for (int e = 0; e < E_; ++e) {
      float v = expf(s[e] - cm[e]);
      for (int off = 32; off; off >>= 1) v += __shfl_xor(v, off);
      if (lane == 0) red[wid][e] = v;
    }
    __syncthreads();
    if (t < E_) {
      float ss = 0.f;
      #pragma unroll
      for (int wv = 0; wv < 16; ++wv) ss += red[wv][t];
      redv[t] = ss;
    }
    __syncthreads();
    #pragma unroll
    for (int e = 0; e < E_; ++e) s[e] -= cm[e] + logf(redv[e]);
    __syncthreads();
  }

  float g[E_]; float rs = 0.f;
  #pragma unroll
  for (int e = 0; e < E_; ++e) { g[e] = expf(s[e]); rs += g[e]; }
  float inv = 1.f / (rs + 1e-8f);
  #pragma unroll
  for (int e = 0; e < E_; ++e) g[e] *= inv;

  int i0 = 0; float v0 = g[0];
  #pragma unroll
  for (int e = 1; e < E_; ++e) if (g[e] > v0) { v0 = g[e]; i0 = e; }
  int i1 = -1; float v1 = -1e30f;
  #pragma unroll
  for (int e = 0; e < E_; ++e) if (e != i0 && g[e] > v1) { v1 = g[e]; i1 = e; }
  float den = 1.f / (v0 + v1 + 1e-8f);
  tkg[row * 2 + 0] = v0 * den; tki[row * 2 + 0] = i0;
  tkg[row * 2 + 1] = v1 * den; tki[row * 2 + 1] = i1;

  atomicAdd(&lcnt[i0], 1);
  atomicAdd(&lcnt[i1], 1);
  __syncthreads();
  if (t < E_) atomicAdd(&cnt[t], lcnt[t]);
}

__global__ void k_offsets(const int* __restrict__ cnt, int* __restrict__ segoff) {
  if (threadIdx.x == 0 && blockIdx.x == 0) {
    int run = 0;
    for (int e = 0; e < E_; ++e) { segoff[e] = run; run += ((cnt[e] + 127) >> 7) << 7; }
    segoff[E_] = run;
  }
}

__global__ __launch_bounds__(256) void k_scatter(const int* __restrict__ tki, const float* __restrict__ tkg,
                                                 const int* __restrict__ segoff, int* __restrict__ cur,
                                                 int* __restrict__ tok, float* __restrict__ gate) {
  int idx = blockIdx.x * 256 + threadIdx.x;    // 8192 pairs
  int row = idx >> 1;
  int e = tki[idx];
  float g = tkg[idx];
  int pos = atomicAdd(&cur[e], 1);
  int p = segoff[e] + pos;
  tok[p] = row;
  gate[p] = g;
}

// ---- big-tile transposes (R14): 128x128 f32 tile, in-LDS transpose ----

// wg & wp -> interleaved wa [e][4096 f'][1024 d]; z = e*2 + iswp
__global__ __launch_bounds__(256) void k_transpose_wgp(const float* __restrict__ wg,
                                                       const float* __restrict__ wp,
                                                       u16* __restrict__ wa) {
  __shared__ __align__(16) u16 ldsT[128][136];
  const int e = blockIdx.z >> 1, iswp = blockIdx.z & 1;
  const float* src = (iswp ? wp : wg) + (size_t)e * D_ * FF_;
  const int woff = iswp * 16;
  const int f0 = blockIdx.x * 128, d0 = blockIdx.y * 128;
  const int tid = threadIdx.x;
  #pragma unroll
  for (int it = 0; it < 16; ++it) {
    const int fi = it * 256 + tid;
    const int rowd = fi >> 5;
    const int col4 = fi & 31;
    const float4 v = *(const float4*)(src + (size_t)(d0 + rowd) * FF_ + f0 + col4 * 4);
    ldsT[col4 * 4 + 0][rowd] = f2bf(v.x);
    ldsT[col4 * 4 + 1][rowd] = f2bf(v.y);
    ldsT[col4 * 4 + 2][rowd] = f2bf(v.z);
    ldsT[col4 * 4 + 3][rowd] = f2bf(v.w);
  }
  __syncthreads();
  const int cl = tid >> 1, half = tid & 1;
  const int f = f0 + cl;
  const int fp = ((f >> 4) << 5) + (f & 15) + woff;
  u16* dst = wa + (size_t)e * 4096 * 1024 + (size_t)fp * 1024 + d0 + half * 64;
  const u16* srcl = &ldsT[cl][half * 64];
  #pragma unroll
  for (int i = 0; i < 8; ++i)
    *(uint4*)(dst + i * 8) = *(const uint4*)(srcl + i * 8);
}

// wo [e][2048 ff][1024 d] -> woT [e][1024 d][2048 ff]
__global__ __launch_bounds__(256) void k_transpose_wo(const float* __restrict__ wo,
                                                      u16* __restrict__ woT) {
  __shared__ __align__(16) u16 ldsT[128][136];
  const int e = blockIdx.z;
  const float* src = wo + (size_t)e * FF_ * D_;
  const int d0 = blockIdx.x * 128, ff0 = blockIdx.y * 128;
  const int tid = threadIdx.x;
  #pragma unroll
  for (int it = 0; it < 16; ++it) {
    const int fi = it * 256 + tid;
    const int rowf = fi >> 5;
    const int col4 = fi & 31;
    const float4 v = *(const float4*)(src + (size_t)(ff0 + rowf) * D_ + d0 + col4 * 4);
    ldsT[col4 * 4 + 0][rowf] = f2bf(v.x);
    ldsT[col4 * 4 + 1][rowf] = f2bf(v.y);
    ldsT[col4 * 4 + 2][rowf] = f2bf(v.z);
    ldsT[col4 * 4 + 3][rowf] = f2bf(v.w);
  }
  __syncthreads();
  const int dl = tid >> 1, half = tid & 1;
  u16* dst = woT + (size_t)e * D_ * FF_ + (size_t)(d0 + dl) * FF_ + ff0 + half * 64;
  const u16* srcl = &ldsT[dl][half * 64];
  #pragma unroll
  for (int i = 0; i < 8; ++i)
    *(uint4*)(dst + i * 8) = *(const uint4*)(srcl + i * 8);
}

// ---- LDS layout (chunk-major, conflict-free, identity gl_lds mapping) ----
// Fragment read = one linear ds_read_b128; 0 conflicts all session.

// ---------------- stage 1: H = relu(X wg) * (X wp)  [R12 verbatim] ----------------
__global__ __launch_bounds__(512, 2) void k_stage1(
    const u16* __restrict__ wa, const u16* __restrict__ xb,
    const int* __restrict__ tok, const int* __restrict__ segoff,
    u16* __restrict__ H) {
  const int raw = blockIdx.x;
  const int e   = raw & 7;           // XCD pin
  const int rem = raw >> 3;          // 0..255
  const int ft  = rem >> 4;          // 0..15
  const int pt2 = rem & 15;          // 0..15
  const int seg0 = segoff[e], segend = segoff[e + 1];
  if (pt2 * 256 >= segend - seg0) return;
  const int tid = threadIdx.x;
  const int lane = tid & 63;
  const int w = tid >> 6;
  const int lane15 = lane & 15, lchunk = lane >> 4;
  const int lk8 = lchunk * 8;
  const int fw = w >> 2, pw = w & 3;

  __shared__ __align__(16) u16 LA[2][16384];
  __shared__ __align__(16) u16 LB[2][16384];   // 128 KB

  const int prow0 = seg0 + pt2 * 256;
  const u16* asrc0 = wa + (size_t)e * 4096 * 1024
                        + (size_t)(ft * 256 + 2 * w * 16 + lane15) * 1024 + lk8;
  const u16* asrc1 = asrc0 + 16 * 1024;
  const int tk0 = tok[prow0 + 2 * w * 16 + lane15];
  const int tk1 = tok[prow0 + 2 * w * 16 + 16 + lane15];
  const u16* bsrc0 = xb + (size_t)tk0 * D_ + lk8;
  const u16* bsrc1 = xb + (size_t)tk1 * D_ + lk8;
  const int dA0 = 2 * w * 512, dA1 = dA0 + 512;   // + kc*8192

  const f32x4 vz = {0.f, 0.f, 0.f, 0.f};
  f32x4 acc[8][4];
  #pragma unroll
  for (int m = 0; m < 8; ++m)
    #pragma unroll
    for (int n = 0; n < 4; ++n) acc[m][n] = vz;

#define STG_A(c, s) do { const int o_ = (s) * 64;           \
    gl_lds16(asrc0 + o_,      &LA[c][dA0]);                 \
    gl_lds16(asrc0 + o_ + 32, &LA[c][dA0 + 8192]);          \
    gl_lds16(asrc1 + o_,      &LA[c][dA1]);                 \
    gl_lds16(asrc1 + o_ + 32, &LA[c][dA1 + 8192]); } while (0)
#define STG_B(c, s) do { const int o_ = (s) * 64;           \
    gl_lds16(bsrc0 + o_,      &LB[c][dA0]);                 \
    gl_lds16(bsrc0 + o_ + 32, &LB[c][dA0 + 8192]);          \
    gl_lds16(bsrc1 + o_,      &LB[c][dA1]);                 \
    gl_lds16(bsrc1 + o_ + 32, &LB[c][dA1 + 8192]); } while (0)

  STG_A(0, 0); STG_B(0, 0);
  #pragma unroll 1
  for (int s = 0; s < NTS1; ++s) {
    const int c = s & 1;
    asm volatile("s_waitcnt vmcnt(0)" ::: "memory");   // step s fully staged
    __builtin_amdgcn_s_barrier();
    asm volatile("" ::: "memory");
    const u16* la = LA[c];
    const u16* lb = LB[c];
    bf16x8 bv[4][2];
    #pragma unroll
    for (int n = 0; n < 4; ++n)
      #pragma unroll
      for (int kc = 0; kc < 2; ++kc)
        bv[n][kc] = *(const bf16x8*)(lb + kc * 8192 + (pw * 4 + n) * 512 + lane * 8);
    #pragma unroll
    for (int p = 0; p < 4; ++p) {
      bf16x8 av[2][2];
      #pragma unroll
      for (int mm = 0; mm < 2; ++mm)
        #pragma unroll
        for (int kc = 0; kc < 2; ++kc)
          av[mm][kc] = *(const bf16x8*)(la + kc * 8192 + (fw * 8 + 2 * p + mm) * 512 + lane * 8);
      if (p == 0) { if (s + 1 < NTS1) STG_A(c ^ 1, s + 1); }
      if (p == 1) { if (s + 1 < NTS1) STG_B(c ^ 1, s + 1); }
      __builtin_amdgcn_s_setprio(1);
      #pragma unroll
      for (int mm = 0; mm < 2; ++mm)
        #pragma unroll
        for (int n = 0; n < 4; ++n)
          #pragma unroll
          for (int kc = 0; kc < 2; ++kc)
            acc[2 * p + mm][n] = MFMA16(av[mm][kc], bv[n][kc], acc[2 * p + mm][n]);
      __builtin_amdgcn_s_setprio(0);
      if (p < 3) {
        __builtin_amdgcn_s_barrier();
        asm volatile("" ::: "memory");
      }
    }
  }
#undef STG_A
#undef STG_B

  const int jrow = lchunk * 4;
  #pragma unroll
  for (int q = 0; q < 4; ++q) {
    const int fcol = ft * 128 + fw * 64 + q * 16 + jrow;
    #pragma unroll
    for (int n = 0; n < 4; ++n) {
      const int prow = prow0 + pw * 64 + n * 16 + lane15;
      if (prow < segend) {
        union { uint2 v; u16 s[4]; } u;
        #pragma unroll
        for (int j = 0; j < 4; ++j)
          u.s[j] = f2bf(fmaxf(acc[2 * q][n][j], 0.f) * acc[2 * q + 1][n][j]);
        *(uint2*)(H + (size_t)prow * FF_ + fcol) = u.v;
      }
    }
  }
}

// ---------------- stage 2: O = (H @ wo) * gate, atomic += into out ----------------
// R15: stage1's phased BK=64 structure on the 128p x 128d tile (576 active
// blocks = 2.25/CU). 2 LDS dbuf 64 KB -> 2 blocks/CU. Per K-step: top
// vmcnt(0)+barrier (only drain), then 2 phases of 8 MFMA/wave with the next
// step's A/B staging split across them. 16 MFMA per drain per wave = 2x R14.
// 8 waves: ph = w>>2 (64 p), dq = w&3 (32 d); acc[4][2].
__global__ __launch_bounds__(512, 2) void k_stage2(
    const u16* __restrict__ H, const u16* __restrict__ woT,
    const int* __restrict__ tok, const float* __restrict__ gate,
    const int* __restrict__ cnt, const int* __restrict__ segoff,
    float* __restrict__ out) {
  const int raw = blockIdx.x;
  const int e   = raw & 7;
  const int rem = raw >> 3;          // 0..255
  const int dt  = rem >> 5;          // 0..7  (128 d each)
  const int pt  = rem & 31;          // 0..31
  if (pt * 128 >= cnt[e]) return;
  const int tid = threadIdx.x;
  const int lane = tid & 63;
  const int w = tid >> 6;
  const int lane15 = lane & 15, lchunk = lane >> 4;
  const int lk8 = lchunk * 8;
  const int ph = w >> 2, dq = w & 3;

  __shared__ __align__(16) u16 LH[2][8192];   // [kc*4096 + rb*512 + lane*8]
  __shared__ __align__(16) u16 LW[2][8192];   // 64 KB
  __shared__ int   ltok[128];
  __shared__ float lgt[128];

  const int prow0 = segoff[e] + pt * 128;
  if (tid < 128) { ltok[tid] = tok[prow0 + tid]; lgt[tid] = gate[prow0 + tid]; }

  // staging: wave w covers rowblock w of H and of woT (2 kc-chunks each)
  const u16* hsrc = H + (size_t)(prow0 + w * 16 + lane15) * FF_ + lk8;
  const u16* wsrc = woT + (size_t)e * D_ * FF_
                        + (size_t)(dt * 128 + w * 16 + lane15) * FF_ + lk8;
  const int dstb = w * 512;                   // + kc*4096

  const f32x4 vz = {0.f, 0.f, 0.f, 0.f};
  f32x4 acc[4][2];
  #pragma unroll
  for (int m = 0; m < 4; ++m)
    #pragma unroll
    for (int n = 0; n < 2; ++n) acc[m][n] = vz;

#define STG_H(c, s) do { const int o_ = (s) * 64;           \
    gl_lds16(hsrc + o_,      &LH[c][dstb]);                 \
    gl_lds16(hsrc + o_ + 32, &LH[c][dstb + 4096]); } while (0)
#define STG_W(c, s) do { const int o_ = (s) * 64;           \
    gl_lds16(wsrc + o_,      &LW[c][dstb]);                 \
    gl_lds16(wsrc + o_ + 32, &LW[c][dstb + 4096]); } while (0)

  STG_H(0, 0); STG_W(0, 0);
  #pragma unroll 1
  for (int s = 0; s < NTS2; ++s) {
    const int c = s & 1;
    asm volatile("s_waitcnt vmcnt(0)" ::: "memory");   // step s fully staged
    __builtin_amdgcn_s_barrier();
    asm volatile("" ::: "memory");
    const u16* lh = LH[c];
    const u16* lw = LW[c];
    bf16x8 bw[2][2];
    #pragma unroll
    for (int n = 0; n < 2; ++n)
      #pragma unroll
      for (int kc = 0; kc < 2; ++kc)
        bw[n][kc] = *(const bf16x8*)(lw + kc * 4096 + (dq * 2 + n) * 512 + lane * 8);
    #pragma unroll
    for (int p = 0; p < 2; ++p) {
      bf16x8 ah[2][2];
      #pragma unroll
      for (int mm = 0; mm < 2; ++mm)
        #pragma unroll
        for (int kc = 0; kc < 2; ++kc)
          ah[mm][kc] = *(const bf16x8*)(lh + kc * 4096 + (ph * 4 + 2 * p + mm) * 512 + lane * 8);
      if (p == 0) { if (s + 1 < NTS2) STG_H(c ^ 1, s + 1); }
      if (p == 1) { if (s + 1 < NTS2) STG_W(c ^ 1, s + 1); }
      __builtin_amdgcn_s_setprio(1);
      #pragma unroll
      for (int mm = 0; mm < 2; ++mm)
        #pragma unroll
        for (int n = 0; n < 2; ++n)
          #pragma unroll
          for (int kc = 0; kc < 2; ++kc)
            acc[2 * p + mm][n] = MFMA16(ah[mm][kc], bw[n][kc], acc[2 * p + mm][n]);
      __builtin_amdgcn_s_setprio(0);
      if (p == 0) {
        __builtin_amdgcn_s_barrier();     // convoy barrier between phases
        asm volatile("" ::: "memory");
      }
    }
  }
#undef STG_H
#undef STG_W

  const int jrow = lchunk * 4;
  #pragma unroll
  for (int m = 0; m < 4; ++m) {
    #pragma unroll
    for (int n = 0; n < 2; ++n) {
      const int dcol = dt * 128 + dq * 32 + n * 16 + lane15;
      #pragma unroll
      for (int j = 0; j < 4; ++j) {
        const int pl = ph * 64 + m * 16 + jrow + j;
        unsafeAtomicAdd(&out[(size_t)ltok[pl] * D_ + dcol], lgt[pl] * acc[m][n][j]);
      }
    }
  }
}

// ---------------- host ----------------

extern "C" void kernel_launch(void* const* d_in, const int* in_sizes, int n_in,
                              void* d_out, int out_size, void* d_ws, size_t ws_size,
                              hipStream_t stream) {
  const float* x    = (const float*)d_in[0];
  const float* rw   = (const float*)d_in[1];
  const float* rb   = (const float*)d_in[2];
  const float* temp = (const float*)d_in[3];
  const float* wg   = (const float*)d_in[4];
  const float* wp   = (const float*)d_in[5];
  const float* wo   = (const float*)d_in[6];
  float* out = (float*)d_out;
  char* ws = (char*)d_ws;

  // workspace layout (bytes)
  const size_t O_XB  = 0;                                  // NT*D bf16        = 8,388,608
  const size_t O_WA  = 8388608;                            // E*4096*1024 bf16 = 67,108,864
  const size_t O_WOT = O_WA;                               // woT reuses wa after stage1
  const size_t O_H   = O_WA + 67108864;                    // LCAP*FF bf16     = 38,797,312
  const size_t O_SC  = O_H + (size_t)LCAP * FF_ * 2;
  const size_t O_TKG = O_SC + (size_t)NT_ * E_ * 4;
  const size_t O_TKI = O_TKG + (size_t)NT_ * 2 * 4;
  const size_t O_CNT = O_TKI + (size_t)NT_ * 2 * 4;
  const size_t O_CUR = O_CNT + 128;
  const size_t O_SEG = O_CUR + 128;
  const size_t O_TOK = O_SEG + 128;
  const size_t O_GTE = O_TOK + (size_t)LCAP * 4;
  const size_t REQ   = O_GTE + (size_t)LCAP * 4;           // ~114.6 MB
  if (ws_size < REQ) return;

  u16*   xb     = (u16*)(ws + O_XB);
  u16*   wa     = (u16*)(ws + O_WA);
  u16*   woT    = (u16*)(ws + O_WOT);
  u16*   Hbuf   = (u16*)(ws + O_H);
  float* scores = (float*)(ws + O_SC);
  float* tkg    = (float*)(ws + O_TKG);
  int*   tki    = (int*)(ws + O_TKI);
  int*   cnt    = (int*)(ws + O_CNT);
  int*   cur    = (int*)(ws + O_CUR);
  int*   segoff = (int*)(ws + O_SEG);
  int*   tok    = (int*)(ws + O_TOK);
  float* gate   = (float*)(ws + O_GTE);

  k_router<<<NT_ / 4, 256, 0, stream>>>(x, rw, rb, temp, scores, out, xb,
                                        tok, gate, cnt, cur);
  k_sinkhorn<<<B_, 1024, 0, stream>>>(scores, tkg, tki, cnt);
  k_offsets<<<1, 64, 0, stream>>>(cnt, segoff);
  k_scatter<<<(NT_ * 2) / 256, 256, 0, stream>>>(tki, tkg, segoff, cur, tok, gate);

  // wg+wp -> interleaved bf16 A (one launch, 128x128 tiles)
  k_transpose_wgp<<<dim3(FF_ / 128, D_ / 128, E_ * 2), 256, 0, stream>>>(wg, wp, wa);

  k_stage1<<<16 * 16 * E_, 512, 0, stream>>>(wa, xb, tok, segoff, Hbuf);

  // wo -> woT (overwrites wa region, dead after stage1)
  k_transpose_wo<<<dim3(D_ / 128, FF_ / 128, E_), 256, 0, stream>>>(wo, woT);

  k_stage2<<<32 * 8 * E_, 512, 0, stream>>>(Hbuf, woT, tok, gate, cnt, segoff, out);
}

// Round 16
// 431.567 us; speedup vs baseline: 1.0794x; 1.0794x over previous
//
#include <hip/hip_runtime.h>
#include <hip/hip_bf16.h>
#include <stdint.h>

// Problem constants
#define B_   4
#define T_   1024
#define D_   1024
#define E_   8
#define FF_  2048
#define NT_  4096            // B*T tokens
#define LCAP 9472            // padded pairs + 256-tile overread headroom
#define NTS1 (D_ / 64)       // 16 K-steps, stage1 (BK=64)
#define NTS2 (FF_ / 64)      // 32 K-steps, stage2 (BK=64)

typedef unsigned short u16;
typedef __attribute__((ext_vector_type(8))) short bf16x8;   // 8 bf16 = 4 VGPRs
typedef __attribute__((ext_vector_type(4))) float f32x4;

#define MFMA16(a, b, c) __builtin_amdgcn_mfma_f32_16x16x32_bf16((a), (b), (c), 0, 0, 0)

__device__ __forceinline__ u16 f2bf(float f) {
  union { float f; uint32_t u; } c; c.f = f;
  return (u16)((c.u + 0x7FFFu + ((c.u >> 16) & 1u)) >> 16);   // RNE
}

__device__ __forceinline__ void gl_lds16(const void* g, void* l) {
  __builtin_amdgcn_global_load_lds(
      (const __attribute__((address_space(1))) uint32_t*)g,
      (__attribute__((address_space(3))) uint32_t*)l, 16, 0, 0);
}

// ---------------- small kernels ----------------

// one wave per token: router scores + out=x copy + xb=bf16(x); absorbs init.
__global__ __launch_bounds__(256) void k_router(const float* __restrict__ x,
                                                const float* __restrict__ rw,
                                                const float* __restrict__ rb,
                                                const float* __restrict__ temp,
                                                float* __restrict__ scores,
                                                float* __restrict__ out,
                                                u16* __restrict__ xb,
                                                int* __restrict__ tok, float* __restrict__ gate,
                                                int* __restrict__ cnt, int* __restrict__ cur) {
  const int gid = blockIdx.x * 256 + threadIdx.x;
  if (gid < LCAP) { tok[gid] = 0; gate[gid] = 0.f; }
  if (gid < E_)   { cnt[gid] = 0; cur[gid] = 0; }

  int wid  = gid >> 6;   // token id
  int lane = threadIdx.x & 63;
  const float* xr = x + (size_t)wid * D_;
  float* orow = out + (size_t)wid * D_;
  u16* xrow = xb + (size_t)wid * D_;
  float acc[E_];
  #pragma unroll
  for (int e = 0; e < E_; ++e) acc[e] = 0.f;
  for (int i = lane; i < D_; i += 64) {
    float xv = xr[i];
    orow[i] = xv;
    xrow[i] = f2bf(xv);
    #pragma unroll
    for (int e = 0; e < E_; ++e) acc[e] += xv * rw[e * D_ + i];
  }
  float inv = 1.0f / fmaxf(temp[0], 0.1f);
  #pragma unroll
  for (int e = 0; e < E_; ++e) {
    float v = acc[e];
    for (int off = 32; off; off >>= 1) v += __shfl_xor(v, off);
    if (lane == 0) scores[(size_t)wid * E_ + e] = (v + rb[e]) * inv;
  }
}

// one block per batch b; thread t owns token row [b,t]; 3 Sinkhorn iters + top-2.
__global__ __launch_bounds__(1024) void k_sinkhorn(const float* __restrict__ scores,
                                                   float* __restrict__ tkg, int* __restrict__ tki,
                                                   int* __restrict__ cnt) {
  const int b = blockIdx.x, t = threadIdx.x;
  const int row = b * T_ + t;
  float s[E_];
  #pragma unroll
  for (int e = 0; e < E_; ++e) s[e] = scores[(size_t)row * E_ + e];

  __shared__ float red[16][E_];
  __shared__ float redv[E_];
  __shared__ int lcnt[E_];
  if (t < E_) lcnt[t] = 0;
  const int wid = t >> 6, lane = t & 63;

  for (int it = 0; it < 3; ++it) {
    float m = s[0];
    #pragma unroll
    for (int e = 1; e < E_; ++e) m = fmaxf(m, s[e]);
    float sum = 0.f;
    #pragma unroll
    for (int e = 0; e < E_; ++e) sum += expf(s[e] - m);
    float lse = m + logf(sum);
    #pragma unroll
    for (int e = 0; e < E_; ++e) s[e] -= lse;

    #pragma unroll
    for (int e = 0; e < E_; ++e) {
      float v = s[e];
      for (int off = 32; off; off >>= 1) v = fmaxf(v, __shfl_xor(v, off));
      if (lane == 0) red[wid][e] = v;
    }
    __syncthreads();
    if (t < E_) {
      float mm = red[0][t];
      #pragma unroll
      for (int wv = 1; wv < 16; ++wv) mm = fmaxf(mm, red[wv][t]);
      redv[t] = mm;
    }
    __syncthreads();
    float cm[E_];
    #pragma unroll
    for (int e = 0; e < E_; ++e) cm[e] = redv[e];

    #pragma unroll
    for (int e = 0; e < E_; ++e) {
      float v = expf(s[e] - cm[e]);
      for (int off = 32; off; off >>= 1) v += __shfl_xor(v, off);
      if (lane == 0) red[wid][e] = v;
    }
    __syncthreads();
    if (t < E_) {
      float ss = 0.f;
      #pragma unroll
      for (int wv = 0; wv < 16; ++wv) ss += red[wv][t];
      redv[t] = ss;
    }
    __syncthreads();
    #pragma unroll
    for (int e = 0; e < E_; ++e) s[e] -= cm[e] + logf(redv[e]);
    __syncthreads();
  }

  float g[E_]; float rs = 0.f;
  #pragma unroll
  for (int e = 0; e < E_; ++e) { g[e] = expf(s[e]); rs += g[e]; }
  float inv = 1.f / (rs + 1e-8f);
  #pragma unroll
  for (int e = 0; e < E_; ++e) g[e] *= inv;

  int i0 = 0; float v0 = g[0];
  #pragma unroll
  for (int e = 1; e < E_; ++e) if (g[e] > v0) { v0 = g[e]; i0 = e; }
  int i1 = -1; float v1 = -1e30f;
  #pragma unroll
  for (int e = 0; e < E_; ++e) if (e != i0 && g[e] > v1) { v1 = g[e]; i1 = e; }
  float den = 1.f / (v0 + v1 + 1e-8f);
  tkg[row * 2 + 0] = v0 * den; tki[row * 2 + 0] = i0;
  tkg[row * 2 + 1] = v1 * den; tki[row * 2 + 1] = i1;

  atomicAdd(&lcnt[i0], 1);
  atomicAdd(&lcnt[i1], 1);
  __syncthreads();
  if (t < E_) atomicAdd(&cnt[t], lcnt[t]);
}

__global__ void k_offsets(const int* __restrict__ cnt, int* __restrict__ segoff) {
  if (threadIdx.x == 0 && blockIdx.x == 0) {
    int run = 0;
    for (int e = 0; e < E_; ++e) { segoff[e] = run; run += ((cnt[e] + 127) >> 7) << 7; }
    segoff[E_] = run;
  }
}

__global__ __launch_bounds__(256) void k_scatter(const int* __restrict__ tki, const float* __restrict__ tkg,
                                                 const int* __restrict__ segoff, int* __restrict__ cur,
                                                 int* __restrict__ tok, float* __restrict__ gate) {
  int idx = blockIdx.x * 256 + threadIdx.x;    // 8192 pairs
  int row = idx >> 1;
  int e = tki[idx];
  float g = tkg[idx];
  int pos = atomicAdd(&cur[e], 1);
  int p = segoff[e] + pos;
  tok[p] = row;
  gate[p] = g;
}

// ---- big-tile transposes (R14): 128x128 f32 tile, in-LDS transpose ----

// wg & wp -> interleaved wa [e][4096 f'][1024 d]; z = e*2 + iswp
__global__ __launch_bounds__(256) void k_transpose_wgp(const float* __restrict__ wg,
                                                       const float* __restrict__ wp,
                                                       u16* __restrict__ wa) {
  __shared__ __align__(16) u16 ldsT[128][136];
  const int e = blockIdx.z >> 1, iswp = blockIdx.z & 1;
  const float* src = (iswp ? wp : wg) + (size_t)e * D_ * FF_;
  const int woff = iswp * 16;
  const int f0 = blockIdx.x * 128, d0 = blockIdx.y * 128;
  const int tid = threadIdx.x;
  #pragma unroll
  for (int it = 0; it < 16; ++it) {
    const int fi = it * 256 + tid;
    const int rowd = fi >> 5;
    const int col4 = fi & 31;
    const float4 v = *(const float4*)(src + (size_t)(d0 + rowd) * FF_ + f0 + col4 * 4);
    ldsT[col4 * 4 + 0][rowd] = f2bf(v.x);
    ldsT[col4 * 4 + 1][rowd] = f2bf(v.y);
    ldsT[col4 * 4 + 2][rowd] = f2bf(v.z);
    ldsT[col4 * 4 + 3][rowd] = f2bf(v.w);
  }
  __syncthreads();
  const int cl = tid >> 1, half = tid & 1;
  const int f = f0 + cl;
  const int fp = ((f >> 4) << 5) + (f & 15) + woff;
  u16* dst = wa + (size_t)e * 4096 * 1024 + (size_t)fp * 1024 + d0 + half * 64;
  const u16* srcl = &ldsT[cl][half * 64];
  #pragma unroll
  for (int i = 0; i < 8; ++i)
    *(uint4*)(dst + i * 8) = *(const uint4*)(srcl + i * 8);
}

// wo [e][2048 ff][1024 d] -> woT [e][1024 d][2048 ff]
__global__ __launch_bounds__(256) void k_transpose_wo(const float* __restrict__ wo,
                                                      u16* __restrict__ woT) {
  __shared__ __align__(16) u16 ldsT[128][136];
  const int e = blockIdx.z;
  const float* src = wo + (size_t)e * FF_ * D_;
  const int d0 = blockIdx.x * 128, ff0 = blockIdx.y * 128;
  const int tid = threadIdx.x;
  #pragma unroll
  for (int it = 0; it < 16; ++it) {
    const int fi = it * 256 + tid;
    const int rowf = fi >> 5;
    const int col4 = fi & 31;
    const float4 v = *(const float4*)(src + (size_t)(ff0 + rowf) * D_ + d0 + col4 * 4);
    ldsT[col4 * 4 + 0][rowf] = f2bf(v.x);
    ldsT[col4 * 4 + 1][rowf] = f2bf(v.y);
    ldsT[col4 * 4 + 2][rowf] = f2bf(v.z);
    ldsT[col4 * 4 + 3][rowf] = f2bf(v.w);
  }
  __syncthreads();
  const int dl = tid >> 1, half = tid & 1;
  u16* dst = woT + (size_t)e * D_ * FF_ + (size_t)(d0 + dl) * FF_ + ff0 + half * 64;
  const u16* srcl = &ldsT[dl][half * 64];
  #pragma unroll
  for (int i = 0; i < 8; ++i)
    *(uint4*)(dst + i * 8) = *(const uint4*)(srcl + i * 8);
}

// ---- LDS layout (chunk-major, conflict-free, identity gl_lds mapping) ----

// ---------------- stage 1: H = relu(X wg) * (X wp)  [R12 verbatim] ----------------
__global__ __launch_bounds__(512, 2) void k_stage1(
    const u16* __restrict__ wa, const u16* __restrict__ xb,
    const int* __restrict__ tok, const int* __restrict__ segoff,
    u16* __restrict__ H) {
  const int raw = blockIdx.x;
  const int e   = raw & 7;           // XCD pin: weight panel locality
  const int rem = raw >> 3;          // 0..255
  const int ft  = rem >> 4;          // 0..15
  const int pt2 = rem & 15;          // 0..15
  const int seg0 = segoff[e], segend = segoff[e + 1];
  if (pt2 * 256 >= segend - seg0) return;
  const int tid = threadIdx.x;
  const int lane = tid & 63;
  const int w = tid >> 6;
  const int lane15 = lane & 15, lchunk = lane >> 4;
  const int lk8 = lchunk * 8;
  const int fw = w >> 2, pw = w & 3;

  __shared__ __align__(16) u16 LA[2][16384];
  __shared__ __align__(16) u16 LB[2][16384];   // 128 KB

  const int prow0 = seg0 + pt2 * 256;
  const u16* asrc0 = wa + (size_t)e * 4096 * 1024
                        + (size_t)(ft * 256 + 2 * w * 16 + lane15) * 1024 + lk8;
  const u16* asrc1 = asrc0 + 16 * 1024;
  const int tk0 = tok[prow0 + 2 * w * 16 + lane15];
  const int tk1 = tok[prow0 + 2 * w * 16 + 16 + lane15];
  const u16* bsrc0 = xb + (size_t)tk0 * D_ + lk8;
  const u16* bsrc1 = xb + (size_t)tk1 * D_ + lk8;
  const int dA0 = 2 * w * 512, dA1 = dA0 + 512;   // + kc*8192

  const f32x4 vz = {0.f, 0.f, 0.f, 0.f};
  f32x4 acc[8][4];
  #pragma unroll
  for (int m = 0; m < 8; ++m)
    #pragma unroll
    for (int n = 0; n < 4; ++n) acc[m][n] = vz;

#define STG_A(c, s) do { const int o_ = (s) * 64;           \
    gl_lds16(asrc0 + o_,      &LA[c][dA0]);                 \
    gl_lds16(asrc0 + o_ + 32, &LA[c][dA0 + 8192]);          \
    gl_lds16(asrc1 + o_,      &LA[c][dA1]);                 \
    gl_lds16(asrc1 + o_ + 32, &LA[c][dA1 + 8192]); } while (0)
#define STG_B(c, s) do { const int o_ = (s) * 64;           \
    gl_lds16(bsrc0 + o_,      &LB[c][dA0]);                 \
    gl_lds16(bsrc0 + o_ + 32, &LB[c][dA0 + 8192]);          \
    gl_lds16(bsrc1 + o_,      &LB[c][dA1]);                 \
    gl_lds16(bsrc1 + o_ + 32, &LB[c][dA1 + 8192]); } while (0)

  STG_A(0, 0); STG_B(0, 0);
  #pragma unroll 1
  for (int s = 0; s < NTS1; ++s) {
    const int c = s & 1;
    asm volatile("s_waitcnt vmcnt(0)" ::: "memory");   // step s fully staged
    __builtin_amdgcn_s_barrier();
    asm volatile("" ::: "memory");
    const u16* la = LA[c];
    const u16* lb = LB[c];
    bf16x8 bv[4][2];
    #pragma unroll
    for (int n = 0; n < 4; ++n)
      #pragma unroll
      for (int kc = 0; kc < 2; ++kc)
        bv[n][kc] = *(const bf16x8*)(lb + kc * 8192 + (pw * 4 + n) * 512 + lane * 8);
    #pragma unroll
    for (int p = 0; p < 4; ++p) {
      bf16x8 av[2][2];
      #pragma unroll
      for (int mm = 0; mm < 2; ++mm)
        #pragma unroll
        for (int kc = 0; kc < 2; ++kc)
          av[mm][kc] = *(const bf16x8*)(la + kc * 8192 + (fw * 8 + 2 * p + mm) * 512 + lane * 8);
      if (p == 0) { if (s + 1 < NTS1) STG_A(c ^ 1, s + 1); }
      if (p == 1) { if (s + 1 < NTS1) STG_B(c ^ 1, s + 1); }
      __builtin_amdgcn_s_setprio(1);
      #pragma unroll
      for (int mm = 0; mm < 2; ++mm)
        #pragma unroll
        for (int n = 0; n < 4; ++n)
          #pragma unroll
          for (int kc = 0; kc < 2; ++kc)
            acc[2 * p + mm][n] = MFMA16(av[mm][kc], bv[n][kc], acc[2 * p + mm][n]);
      __builtin_amdgcn_s_setprio(0);
      if (p < 3) {
        __builtin_amdgcn_s_barrier();
        asm volatile("" ::: "memory");
      }
    }
  }
#undef STG_A
#undef STG_B

  const int jrow = lchunk * 4;
  #pragma unroll
  for (int q = 0; q < 4; ++q) {
    const int fcol = ft * 128 + fw * 64 + q * 16 + jrow;
    #pragma unroll
    for (int n = 0; n < 4; ++n) {
      const int prow = prow0 + pw * 64 + n * 16 + lane15;
      if (prow < segend) {
        union { uint2 v; u16 s[4]; } u;
        #pragma unroll
        for (int j = 0; j < 4; ++j)
          u.s[j] = f2bf(fmaxf(acc[2 * q][n][j], 0.f) * acc[2 * q + 1][n][j]);
        *(uint2*)(H + (size_t)prow * FF_ + fcol) = u.v;
      }
    }
  }
}

// ---------------- stage 2: O = (H @ wo) * gate, atomic += into out ----------------
// R15 structure; XCD REMAP: raw&7 = dt (not e). Each XCD owns one 128-d slice
// of ALL experts: woT working set per XCD = 8e x 128d x 2048ff x 2B = 4 MB =
// exactly L2-resident. H becomes a once-per-XCD stream (latency-tolerant via
// the existing prefetch). Previously (pin by e) the per-XCD set was 16 MB ->
// constant L2 misses on BOTH operands.
__global__ __launch_bounds__(512, 2) void k_stage2(
    const u16* __restrict__ H, const u16* __restrict__ woT,
    const int* __restrict__ tok, const float* __restrict__ gate,
    const int* __restrict__ cnt, const int* __restrict__ segoff,
    float* __restrict__ out) {
  const int raw = blockIdx.x;
  const int dt  = raw & 7;           // XCD pin: d-slice locality
  const int rem = raw >> 3;          // 0..255
  const int e   = rem >> 5;          // 0..7
  const int pt  = rem & 31;          // 0..31
  if (pt * 128 >= cnt[e]) return;
  const int tid = threadIdx.x;
  const int lane = tid & 63;
  const int w = tid >> 6;
  const int lane15 = lane & 15, lchunk = lane >> 4;
  const int lk8 = lchunk * 8;
  const int ph = w >> 2, dq = w & 3;

  __shared__ __align__(16) u16 LH[2][8192];   // [kc*4096 + rb*512 + lane*8]
  __shared__ __align__(16) u16 LW[2][8192];   // 64 KB
  __shared__ int   ltok[128];
  __shared__ float lgt[128];

  const int prow0 = segoff[e] + pt * 128;
  if (tid < 128) { ltok[tid] = tok[prow0 + tid]; lgt[tid] = gate[prow0 + tid]; }

  const u16* hsrc = H + (size_t)(prow0 + w * 16 + lane15) * FF_ + lk8;
  const u16* wsrc = woT + (size_t)e * D_ * FF_
                        + (size_t)(dt * 128 + w * 16 + lane15) * FF_ + lk8;
  const int dstb = w * 512;                   // + kc*4096

  const f32x4 vz = {0.f, 0.f, 0.f, 0.f};
  f32x4 acc[4][2];
  #pragma unroll
  for (int m = 0; m < 4; ++m)
    #pragma unroll
    for (int n = 0; n < 2; ++n) acc[m][n] = vz;

#define STG_H(c, s) do { const int o_ = (s) * 64;           \
    gl_lds16(hsrc + o_,      &LH[c][dstb]);                 \
    gl_lds16(hsrc + o_ + 32, &LH[c][dstb + 4096]); } while (0)
#define STG_W(c, s) do { const int o_ = (s) * 64;           \
    gl_lds16(wsrc + o_,      &LW[c][dstb]);                 \
    gl_lds16(wsrc + o_ + 32, &LW[c][dstb + 4096]); } while (0)

  STG_H(0, 0); STG_W(0, 0);
  #pragma unroll 1
  for (int s = 0; s < NTS2; ++s) {
    const int c = s & 1;
    asm volatile("s_waitcnt vmcnt(0)" ::: "memory");   // step s fully staged
    __builtin_amdgcn_s_barrier();
    asm volatile("" ::: "memory");
    const u16* lh = LH[c];
    const u16* lw = LW[c];
    bf16x8 bw[2][2];
    #pragma unroll
    for (int n = 0; n < 2; ++n)
      #pragma unroll
      for (int kc = 0; kc < 2; ++kc)
        bw[n][kc] = *(const bf16x8*)(lw + kc * 4096 + (dq * 2 + n) * 512 + lane * 8);
    #pragma unroll
    for (int p = 0; p < 2; ++p) {
      bf16x8 ah[2][2];
      #pragma unroll
      for (int mm = 0; mm < 2; ++mm)
        #pragma unroll
        for (int kc = 0; kc < 2; ++kc)
          ah[mm][kc] = *(const bf16x8*)(lh + kc * 4096 + (ph * 4 + 2 * p + mm) * 512 + lane * 8);
      if (p == 0) { if (s + 1 < NTS2) STG_H(c ^ 1, s + 1); }
      if (p == 1) { if (s + 1 < NTS2) STG_W(c ^ 1, s + 1); }
      __builtin_amdgcn_s_setprio(1);
      #pragma unroll
      for (int mm = 0; mm < 2; ++mm)
        #pragma unroll
        for (int n = 0; n < 2; ++n)
          #pragma unroll
          for (int kc = 0; kc < 2; ++kc)
            acc[2 * p + mm][n] = MFMA16(ah[mm][kc], bw[n][kc], acc[2 * p + mm][n]);
      __builtin_amdgcn_s_setprio(0);
      if (p == 0) {
        __builtin_amdgcn_s_barrier();     // convoy barrier between phases
        asm volatile("" ::: "memory");
      }
    }
  }
#undef STG_H
#undef STG_W

  const int jrow = lchunk * 4;
  #pragma unroll
  for (int m = 0; m < 4; ++m) {
    #pragma unroll
    for (int n = 0; n < 2; ++n) {
      const int dcol = dt * 128 + dq * 32 + n * 16 + lane15;
      #pragma unroll
      for (int j = 0; j < 4; ++j) {
        const int pl = ph * 64 + m * 16 + jrow + j;
        unsafeAtomicAdd(&out[(size_t)ltok[pl] * D_ + dcol], lgt[pl] * acc[m][n][j]);
      }
    }
  }
}

// ---------------- host ----------------

extern "C" void kernel_launch(void* const* d_in, const int* in_sizes, int n_in,
                              void* d_out, int out_size, void* d_ws, size_t ws_size,
                              hipStream_t stream) {
  const float* x    = (const float*)d_in[0];
  const float* rw   = (const float*)d_in[1];
  const float* rb   = (const float*)d_in[2];
  const float* temp = (const float*)d_in[3];
  const float* wg   = (const float*)d_in[4];
  const float* wp   = (const float*)d_in[5];
  const float* wo   = (const float*)d_in[6];
  float* out = (float*)d_out;
  char* ws = (char*)d_ws;

  // workspace layout (bytes)
  const size_t O_XB  = 0;                                  // NT*D bf16        = 8,388,608
  const size_t O_WA  = 8388608;                            // E*4096*1024 bf16 = 67,108,864
  const size_t O_WOT = O_WA;                               // woT reuses wa after stage1
  const size_t O_H   = O_WA + 67108864;                    // LCAP*FF bf16     = 38,797,312
  const size_t O_SC  = O_H + (size_t)LCAP * FF_ * 2;
  const size_t O_TKG = O_SC + (size_t)NT_ * E_ * 4;
  const size_t O_TKI = O_TKG + (size_t)NT_ * 2 * 4;
  const size_t O_CNT = O_TKI + (size_t)NT_ * 2 * 4;
  const size_t O_CUR = O_CNT + 128;
  const size_t O_SEG = O_CUR + 128;
  const size_t O_TOK = O_SEG + 128;
  const size_t O_GTE = O_TOK + (size_t)LCAP * 4;
  const size_t REQ   = O_GTE + (size_t)LCAP * 4;           // ~114.6 MB
  if (ws_size < REQ) return;

  u16*   xb     = (u16*)(ws + O_XB);
  u16*   wa     = (u16*)(ws + O_WA);
  u16*   woT    = (u16*)(ws + O_WOT);
  u16*   Hbuf   = (u16*)(ws + O_H);
  float* scores = (float*)(ws + O_SC);
  float* tkg    = (float*)(ws + O_TKG);
  int*   tki    = (int*)(ws + O_TKI);
  int*   cnt    = (int*)(ws + O_CNT);
  int*   cur    = (int*)(ws + O_CUR);
  int*   segoff = (int*)(ws + O_SEG);
  int*   tok    = (int*)(ws + O_TOK);
  float* gate   = (float*)(ws + O_GTE);

  k_router<<<NT_ / 4, 256, 0, stream>>>(x, rw, rb, temp, scores, out, xb,
                                        tok, gate, cnt, cur);
  k_sinkhorn<<<B_, 1024, 0, stream>>>(scores, tkg, tki, cnt);
  k_offsets<<<1, 64, 0, stream>>>(cnt, segoff);
  k_scatter<<<(NT_ * 2) / 256, 256, 0, stream>>>(tki, tkg, segoff, cur, tok, gate);

  // wg+wp -> interleaved bf16 A (one launch, 128x128 tiles)
  k_transpose_wgp<<<dim3(FF_ / 128, D_ / 128, E_ * 2), 256, 0, stream>>>(wg, wp, wa);

  k_stage1<<<16 * 16 * E_, 512, 0, stream>>>(wa, xb, tok, segoff, Hbuf);

  // wo -> woT (overwrites wa region, dead after stage1)
  k_transpose_wo<<<dim3(D_ / 128, FF_ / 128, E_), 256, 0, stream>>>(wo, woT);

  k_stage2<<<32 * 8 * E_, 512, 0, stream>>>(Hbuf, woT, tok, gate, cnt, segoff, out);
}